// Round 7
// baseline (66.485 us; speedup 1.0000x reference)
//
#include <hip/hip_runtime.h>

#define KK 16
#define NPIX 16384   // 128*128

// ws layout (no zero-init required — K1 initializes acc/cnt, partials overwritten):
//   [0     .. 4095 ]  : int   maxpart[64*16]  per-4-row-block per-k D2 max,
//                              index = (b*32 + rb)*16 + k
//   [16384 .. 16387]  : float acc   loss accumulator (K1 inits to 0)
//   [16388 .. 16391]  : uint  cnt   ticket counter   (K1 inits to 0)
//   [20480 .. +64KB]  : u16   d2own[32768]  squared dist to nearest differing label
//
// Key identity: gt at pixel p depends only on k = mask[p]-1 (bins are ANDed with
// nuclei), and max_k(d) is over instance-k pixels only. So the only EDT values
// ever consumed are D2_own[p] = min over q with mask[q] != mask[p] of |p-q|^2.

__global__ __launch_bounds__(256) void edt_own_kernel(const int* __restrict__ mask,
                                                      int* __restrict__ maxpart,
                                                      float* __restrict__ acc,
                                                      unsigned int* __restrict__ cnt,
                                                      unsigned short* __restrict__ d2own) {
    __shared__ int lab[6][128];   // rows r0-1 .. r0+4 (255 = outside image)
    __shared__ int lmax[KK];

    const int bid = blockIdx.x;       // 0..63 = b*32 + rb
    const int t   = threadIdx.x;      // 0..255
    const int b   = bid >> 5;
    const int rb  = bid & 31;
    const int r0  = rb * 4;

    if (bid == 0 && t == 0) { *acc = 0.0f; *cnt = 0u; }  // init for K2
                                                         // (kernel boundary = visibility)
    if (t < KK) lmax[t] = 0;

    // stage 6 rows (each mask row loaded once per block)
    const int* mimg = mask + b * NPIX;
    #pragma unroll
    for (int s = t; s < 768; s += 256) {
        const int q = s >> 7, col = s & 127;
        const int rr = r0 - 1 + q;
        lab[q][col] = (rr >= 0 && rr <= 127) ? mimg[rr * 128 + col] : 255;
    }
    __syncthreads();

    const int h = t >> 7;             // 0/1: thread owns rows r0+h and r0+h+2
    const int j = t & 127;            // column

    int best[2], lv[2], rowv[2];
    #pragma unroll
    for (int hh = 0; hh < 2; ++hh) {
        const int lr = 1 + h + 2 * hh;    // local row index in lab
        rowv[hh] = r0 + h + 2 * hh;
        const int l = lab[lr][j];
        lv[hh] = l;
        int bst;
        if (l == 0) {
            bst = 0;                  // background pixel: EDT value never consumed
        } else {
            bst = 0x7fffffff;
            // ---- ring 1: 8 neighbors from LDS (d2 = 1 or 2) ----
            const int lf = (j > 0)   ? lab[lr][j - 1] : l;   // own-label = invalid
            const int rt = (j < 127) ? lab[lr][j + 1] : l;
            if (lf != l) bst = 1;
            if (rt != l) bst = 1;
            const int up = lab[lr - 1][j];
            const int dn = lab[lr + 1][j];
            if (up != l && up != 255) bst = min(bst, 1);
            if (dn != l && dn != 255) bst = min(bst, 1);
            const int ul = (j > 0)   ? lab[lr - 1][j - 1] : 255;
            const int ur = (j < 127) ? lab[lr - 1][j + 1] : 255;
            const int dl = (j > 0)   ? lab[lr + 1][j - 1] : 255;
            const int dr = (j < 127) ? lab[lr + 1][j + 1] : 255;
            if (ul != l && ul != 255) bst = min(bst, 2);
            if (ur != l && ur != 255) bst = min(bst, 2);
            if (dl != l && dl != 255) bst = min(bst, 2);
            if (dr != l && dr != 255) bst = min(bst, 2);
        }
        best[hh] = bst;
    }

    // ---- expanding Chebyshev rings (exact; ~never executes on random labels) ----
    // After ring e-1, unexamined pixels have d2 >= e^2 -> continue iff e^2 < best.
    for (int e = 2; e < 128; ++e) {
        if (!__any(e * e < max(best[0], best[1]))) break;
        #pragma unroll
        for (int hh = 0; hh < 2; ++hh) {
            if (e * e < best[hh]) {
                const int l = lv[hh], r = rowv[hh];
                int bst = best[hh];
                for (int di = -e; di <= e; ++di) {
                    const int rr = r + di;
                    if (rr < 0 || rr > 127) continue;
                    const int* rw = mimg + rr * 128;
                    const int ad = (di < 0) ? -di : di;
                    if (ad == e) {
                        const int j0 = max(j - e, 0), j1 = min(j + e, 127);
                        for (int jj = j0; jj <= j1; ++jj) {
                            if (rw[jj] != l) {
                                const int dj = jj - j;
                                bst = min(bst, di * di + dj * dj);
                            }
                        }
                    } else {
                        const int jl = j - e, jr = j + e;
                        if (jl >= 0   && rw[jl] != l) bst = min(bst, di * di + e * e);
                        if (jr <= 127 && rw[jr] != l) bst = min(bst, di * di + e * e);
                    }
                }
                best[hh] = bst;
            }
        }
    }

    #pragma unroll
    for (int hh = 0; hh < 2; ++hh) {
        const int bst = min(best[hh], 40000);   // uniform-image sentinel (= 200^2)
        d2own[b * NPIX + rowv[hh] * 128 + j] = (unsigned short)bst;
        if (lv[hh] > 0) atomicMax(&lmax[lv[hh] - 1], bst);
    }
    __syncthreads();
    if (t < KK) maxpart[bid * KK + t] = lmax[t];
}

// Disjoint-support gt+loss: each pixel belongs to at most ONE instance, so gt has
// exactly one nonzero channel, selected by the pixel's own label.
// 64 blocks x 256 threads, 2 consecutive pixels/thread, vectorized 8B loads.
// (out stores stay scalar: the +1 loss-scalar offset leaves gt only 4B-aligned.)
__global__ __launch_bounds__(256) void gt_loss_kernel(const float* __restrict__ pred,
                                                      const float* __restrict__ ign,
                                                      const int* __restrict__ mask,
                                                      const unsigned short* __restrict__ d2own,
                                                      const int* __restrict__ maxpart,
                                                      float* __restrict__ out,
                                                      float* __restrict__ acc,
                                                      unsigned int* __restrict__ cnt) {
    __shared__ int   lmax2[KK];
    __shared__ float msq[KK];
    __shared__ float wred[4];

    const int bid = blockIdx.x;           // 0..63
    const int t   = threadIdx.x;          // 0..255
    const int b   = bid >> 5;             // 0..1  (all pixels of a block share b)
    const int pp  = (bid & 31) * 512 + 2 * t;   // even pixel index within image
    const int p   = b * NPIX + pp;              // global pixel (even)

    // msq[k] = sqrt(max D2) for this b: reduce 32 row-block partials.
    // threads t<64 -> (k = t&15, chunk c = t>>4): 4 threads/k x 8 row-blocks each.
    if (t < KK) lmax2[t] = 0;
    __syncthreads();
    if (t < 64) {
        const int k = t & 15, c = t >> 4;
        const int* mp = maxpart + b * (32 * KK) + c * (8 * KK) + k;
        int pm = 0;
        #pragma unroll
        for (int rr = 0; rr < 8; ++rr) pm = max(pm, mp[rr * KK]);
        atomicMax(&lmax2[k], pm);
    }
    __syncthreads();
    if (t < KK) msq[t] = __fsqrt_rn((float)lmax2[t]);
    __syncthreads();

    const int2    lab2 = *(const int2*)(mask + p);
    const ushort2 dd2  = *(const ushort2*)(d2own + p);
    const float2  ig2  = *(const float2*)(ign + p);

    const int labs[2] = {lab2.x, lab2.y};
    const int d2s[2]  = {(int)dd2.x, (int)dd2.y};
    int cbin[2] = {-1, -1};
    #pragma unroll
    for (int s = 0; s < 2; ++s) {
        if (labs[s] > 0) {
            const float d  = __fsqrt_rn((float)d2s[s]);     // D2 >= 1 on instances
            float dn = __fdiv_rn(d, msq[labs[s] - 1]);      // msq >= 1 since max >= 1
            if (dn < 0.5f) dn = 0.0f;
            if (dn > 0.7f) dn = 1.0f;
            const float ddd[8] = {0.83f, 0.68f, 0.54f, 0.41f, 0.29f, 0.18f, 0.09f, 0.0f};
            #pragma unroll
            for (int c = 0; c < 8; ++c) {
                if (cbin[s] < 0 && dn >= ddd[c]) cbin[s] = c;
            }
        }
    }

    float lsum0 = 0.0f, lsum1 = 0.0f;
    #pragma unroll
    for (int c = 0; c < 8; ++c) {
        const float g0 = (c == cbin[0]) ? 1.0f : 0.0f;
        const float g1 = (c == cbin[1]) ? 1.0f : 0.0f;
        const int base = (b * 8 + c) * NPIX + pp;
        out[1 + base]     = g0;
        out[1 + base + 1] = g1;
        const float2 pr2 = *(const float2*)(pred + base);
        const float diff0 = pr2.x - g0;
        const float diff1 = pr2.y - g1;
        const float ad0 = fabsf(diff0);
        const float ad1 = fabsf(diff1);
        lsum0 += (ad0 < 1.0f) ? 0.5f * diff0 * diff0 : (ad0 - 0.5f);
        lsum1 += (ad1 < 1.0f) ? 0.5f * diff1 * diff1 : (ad1 - 0.5f);
    }
    float contrib = (lsum0 * ig2.x + lsum1 * ig2.y) * 0.125f;

    #pragma unroll
    for (int off = 32; off; off >>= 1) contrib += __shfl_down(contrib, off, 64);
    if ((t & 63) == 0) wred[t >> 6] = contrib;
    __syncthreads();

    if (t == 0) {
        atomicAdd(acc, (wred[0] + wred[1]) + (wred[2] + wred[3]));
        __threadfence();
        const unsigned int old = atomicAdd(cnt, 1u);
        if (old == 63u) {                         // last block: all adds visible
            const float total = atomicAdd(acc, 0.0f);
            out[0] = total * (1.0f / 32768.0f);
        }
    }
}

extern "C" void kernel_launch(void* const* d_in, const int* in_sizes, int n_in,
                              void* d_out, int out_size, void* d_ws, size_t ws_size,
                              hipStream_t stream) {
    const float* pred = (const float*)d_in[0];
    const int*   mask = (const int*)d_in[1];
    const float* ign  = (const float*)d_in[2];
    float* out = (float*)d_out;

    int*            maxpart = (int*)d_ws;
    float*          acc     = (float*)((char*)d_ws + 16384);
    unsigned int*   cnt     = (unsigned int*)((char*)d_ws + 16388);
    unsigned short* d2own   = (unsigned short*)((char*)d_ws + 20480);

    edt_own_kernel<<<64, 256, 0, stream>>>(mask, maxpart, acc, cnt, d2own);
    gt_loss_kernel<<<64, 256, 0, stream>>>(pred, ign, mask, d2own, maxpart, out, acc, cnt);
}